// Round 10
// baseline (395.327 us; speedup 1.0000x reference)
//
#include <hip/hip_runtime.h>

#define HDIM 2048
#define HH (HDIM * HDIM)          // 4,194,304
#define NIDX 2000000
#define BINS 256
#define NCOPY 16
#define TL_BLOCKS 2048
#define NCHUNK 2000               // sort chunks: 1000 samples each (250 int4)
#define CH_I4 250
#define NWIN 64                   // window = pd>>16 (64K pixels; ~1MB floats+mask)

// workspace layout (bytes) — ~14.7 MB
#define PART_OFF   0                        // double partials[2048] = 16 KB
#define TAB_OFF    16384                    // float tab[3*BINS]
#define WGL_OFF    20480                    // uint W_d[65] + W_r[65]
#define HIST_OFF   24576                    // uint hist[16][6][256] = 96 KB
#define CNT_D_OFF  131072                   // ushort cnt_d[2000][64] = 256 KB
#define CNT_R_OFF  393216
#define OFF_D_OFF  655360                   // uint off_d[2000][64] = 512 KB
#define OFF_R_OFF  1179648
#define FLAGS_OFF  2097152                  // uchar flags[HH] = 4 MB
#define SORT_D_OFF 6291456                  // ushort sorted_d[NIDX] = 4 MB
#define SORT_R_OFF 10485760                 // ushort sorted_r[NIDX] = 4 MB (ends 14.68 MB)

// Node 1: zero hist/flags + per-chunk window COUNTS (block-owned LDS, no
// global atomics). No image packing anymore (R10: whist gathers floats
// directly from L2-resident windows).
__global__ __launch_bounds__(256) void prep_kernel(
    const int* __restrict__ i0, const int* __restrict__ i1,
    const int* __restrict__ i2, const int* __restrict__ i3,
    unsigned* __restrict__ hist, unsigned* __restrict__ flags32,
    unsigned short* __restrict__ cnt_d, unsigned short* __restrict__ cnt_r)
{
    __shared__ unsigned cntd[NWIN], cntr[NWIN];
    const int t = threadIdx.x;
    const int gtid = blockIdx.x * 256 + t;
    const int stride = gridDim.x * 256;

    for (int k = gtid; k < NCOPY * 6 * BINS; k += stride) hist[k] = 0;
    for (int k = gtid; k < HH / 4; k += stride) flags32[k] = 0;

    if (blockIdx.x < NCHUNK) {
        if (t < NWIN) { cntd[t] = 0; cntr[t] = 0; }
        __syncthreads();
        if (t < CH_I4) {
            const int q = blockIdx.x * CH_I4 + t;
            const int4 a = ((const int4*)i0)[q];
            const int4 b = ((const int4*)i1)[q];
            const int4 c = ((const int4*)i2)[q];
            const int4 d = ((const int4*)i3)[q];
            const int pd[4] = {a.x * HDIM + b.x, a.y * HDIM + b.y, a.z * HDIM + b.z, a.w * HDIM + b.w};
            const int pr[4] = {c.x * HDIM + d.x, c.y * HDIM + d.y, c.z * HDIM + d.z, c.w * HDIM + d.w};
#pragma unroll
            for (int k = 0; k < 4; k++) atomicAdd(&cntd[pd[k] >> 16], 1u);
#pragma unroll
            for (int k = 0; k < 4; k++) atomicAdd(&cntr[pr[k] >> 16], 1u);
        }
        __syncthreads();
        if (t < NWIN) {
            cnt_d[blockIdx.x * NWIN + t] = (unsigned short)cntd[t];
            cnt_r[blockIdx.x * NWIN + t] = (unsigned short)cntr[t];
        }
    }
}

// Node 2: exact global offsets (1 block; deterministic integer prefix sums).
__global__ __launch_bounds__(1024) void off_kernel(
    const unsigned short* __restrict__ cnt_d, const unsigned short* __restrict__ cnt_r,
    unsigned* __restrict__ off_d, unsigned* __restrict__ off_r, unsigned* __restrict__ Wg)
{
    __shared__ unsigned psum[16][NWIN];
    __shared__ unsigned segbase[16][NWIN];
    __shared__ unsigned Wl[NWIN + 1];
    const int t = threadIdx.x;
    const int w = t & 63, seg = t >> 6;          // 16 segments x 125 chunks

    for (int side = 0; side < 2; side++) {
        const unsigned short* cnt = side ? cnt_r : cnt_d;
        unsigned* off = side ? off_r : off_d;
        unsigned s = 0;
        for (int b = seg * 125; b < seg * 125 + 125; b++) s += cnt[b * NWIN + w];
        psum[seg][w] = s;
        __syncthreads();
        if (t < NWIN) {
            unsigned run = 0;
            for (int sg = 0; sg < 16; sg++) { segbase[sg][t] = run; run += psum[sg][t]; }
            unsigned inc = run;                   // inclusive scan over w (wave64)
            for (int d = 1; d < 64; d <<= 1) {
                const unsigned y = __shfl_up(inc, d, 64);
                if (t >= d) inc += y;
            }
            Wl[t] = inc - run;                    // exclusive
            if (t == 63) Wl[64] = inc;            // total = NIDX
        }
        __syncthreads();
        unsigned run = Wl[w] + segbase[seg][w];
        for (int b = seg * 125; b < seg * 125 + 125; b++) {
            off[b * NWIN + w] = run;
            run += cnt[b * NWIN + w];
        }
        if (t < NWIN + 1) Wg[side * (NWIN + 1) + t] = Wl[t];
        __syncthreads();
    }
}

// Node 3: place each sample into its exact sorted slot (LDS cursors only).
__global__ __launch_bounds__(256) void place_kernel(
    const int* __restrict__ i0, const int* __restrict__ i1,
    const int* __restrict__ i2, const int* __restrict__ i3,
    const unsigned* __restrict__ off_d, const unsigned* __restrict__ off_r,
    unsigned short* __restrict__ sorted_d, unsigned short* __restrict__ sorted_r)
{
    __shared__ unsigned cur[NWIN];
    const int b = blockIdx.x;
    const int t = threadIdx.x;

    if (t < NWIN) cur[t] = off_d[b * NWIN + t];
    __syncthreads();
    if (t < CH_I4) {
        const int q = b * CH_I4 + t;
        const int4 a = ((const int4*)i0)[q];
        const int4 bb = ((const int4*)i1)[q];
        const int pd[4] = {a.x * HDIM + bb.x, a.y * HDIM + bb.y, a.z * HDIM + bb.z, a.w * HDIM + bb.w};
#pragma unroll
        for (int k = 0; k < 4; k++) {
            const unsigned pos = atomicAdd(&cur[pd[k] >> 16], 1u);
            sorted_d[pos] = (unsigned short)(pd[k] & 0xFFFF);
        }
    }
    __syncthreads();
    if (t < NWIN) cur[t] = off_r[b * NWIN + t];
    __syncthreads();
    if (t < CH_I4) {
        const int q = b * CH_I4 + t;
        const int4 c = ((const int4*)i2)[q];
        const int4 d = ((const int4*)i3)[q];
        const int pr[4] = {c.x * HDIM + d.x, c.y * HDIM + d.y, c.z * HDIM + d.z, c.w * HDIM + d.w};
#pragma unroll
        for (int k = 0; k < 4; k++) {
            const unsigned pos = atomicAdd(&cur[pr[k] >> 16], 1u);
            sorted_r[pos] = (unsigned short)(pr[k] & 0xFFFF);
        }
    }
}

// Node 4: XCD-PARTITIONED sorted gather, floats direct. Window w is touched
// ONLY by blocks with blockIdx%8 == w%8 (blockIdx%8 ~ XCD round-robin) ->
// each window's ~1MB (3 channels + mask) resides in exactly ONE XCD L2
// (R9 counter evidence: unpartitioned sorted walk duplicated every line
// ~5.3x across XCDs -> 169MB FETCH). Class reads only its own contiguous
// sorted segments (1/8 of the 8MB). Bin math = validated pack math.
// Bin-0 in registers; flags idempotent bytes (window-local); 16-copy flush.
__global__ __launch_bounds__(256) void whist_kernel(
    const float* __restrict__ ref, const float* __restrict__ tgt,
    const float* __restrict__ msrc, const float* __restrict__ mtar,
    const unsigned short* __restrict__ sorted_d, const unsigned short* __restrict__ sorted_r,
    const unsigned* __restrict__ Wg,
    unsigned char* __restrict__ flags, unsigned* __restrict__ hist)
{
    __shared__ unsigned lhist[6 * BINS];
    __shared__ unsigned Ws[2 * (NWIN + 1)];
    const int t = threadIdx.x;
    for (int k = t; k < 6 * BINS; k += 256) lhist[k] = 0;
    if (t < 2 * (NWIN + 1)) Ws[t] = Wg[t];
    __syncthreads();

    unsigned z0 = 0, z1 = 0, z2 = 0, z3 = 0, z4 = 0, z5 = 0;
    const int cls = blockIdx.x & 7;        // ~XCD id
    const int bc  = blockIdx.x >> 3;       // 0..255 within class
    const int cstep = 256 * 256;           // class-wide thread count

    // ---- d side: ref/msrc, bins 0..2 + flags ----
    for (int w = cls; w < NWIN; w += 8) {
        const int base = w << 16;
        const int e0 = (int)Ws[w], e1 = (int)Ws[w + 1];
        for (int e = e0 + bc * 256 + t; e < e1; e += cstep) {
            const int pd = base | (int)sorted_d[e];
            const float mm = msrc[pd];
            const float v0 = ref[pd], v1 = ref[HH + pd], v2 = ref[2 * HH + pd];
            flags[pd] = 1;
            const float f0 = ((v0 + 1.0f) * 0.5f) * 255.0f * mm;
            const float f1 = ((v1 + 1.0f) * 0.5f) * 255.0f * mm;
            const float f2 = ((v2 + 1.0f) * 0.5f) * 255.0f * mm;
            const unsigned b0 = (unsigned)(int)fminf(fmaxf(floorf(f0), 0.0f), 255.0f);
            const unsigned b1 = (unsigned)(int)fminf(fmaxf(floorf(f1), 0.0f), 255.0f);
            const unsigned b2 = (unsigned)(int)fminf(fmaxf(floorf(f2), 0.0f), 255.0f);
            if (b0) atomicAdd(&lhist[           b0], 1u); else z0++;
            if (b1) atomicAdd(&lhist[1 * BINS + b1], 1u); else z1++;
            if (b2) atomicAdd(&lhist[2 * BINS + b2], 1u); else z2++;
        }
    }
    // ---- r side: tgt/mtar, bins 3..5 ----
    for (int w = cls; w < NWIN; w += 8) {
        const int base = w << 16;
        const int e0 = (int)Ws[NWIN + 1 + w], e1 = (int)Ws[NWIN + 1 + w + 1];
        for (int e = e0 + bc * 256 + t; e < e1; e += cstep) {
            const int pr = base | (int)sorted_r[e];
            const float mm = mtar[pr];
            const float v0 = tgt[pr], v1 = tgt[HH + pr], v2 = tgt[2 * HH + pr];
            const float f0 = ((v0 + 1.0f) * 0.5f) * 255.0f * mm;
            const float f1 = ((v1 + 1.0f) * 0.5f) * 255.0f * mm;
            const float f2 = ((v2 + 1.0f) * 0.5f) * 255.0f * mm;
            const unsigned b0 = (unsigned)(int)fminf(fmaxf(floorf(f0), 0.0f), 255.0f);
            const unsigned b1 = (unsigned)(int)fminf(fmaxf(floorf(f1), 0.0f), 255.0f);
            const unsigned b2 = (unsigned)(int)fminf(fmaxf(floorf(f2), 0.0f), 255.0f);
            if (b0) atomicAdd(&lhist[3 * BINS + b0], 1u); else z3++;
            if (b1) atomicAdd(&lhist[4 * BINS + b1], 1u); else z4++;
            if (b2) atomicAdd(&lhist[5 * BINS + b2], 1u); else z5++;
        }
    }

    if (z0) atomicAdd(&lhist[0 * BINS], z0);
    if (z1) atomicAdd(&lhist[1 * BINS], z1);
    if (z2) atomicAdd(&lhist[2 * BINS], z2);
    if (z3) atomicAdd(&lhist[3 * BINS], z3);
    if (z4) atomicAdd(&lhist[4 * BINS], z4);
    if (z5) atomicAdd(&lhist[5 * BINS], z5);
    __syncthreads();
    unsigned* h = hist + (blockIdx.x & (NCOPY - 1)) * (6 * BINS);
    for (int k = t; k < 6 * BINS; k += 256) {
        const unsigned v = lhist[k];
        if (v) atomicAdd(&h[k], v);
    }
}

// Node 5: transfer table (1 block). Validated logic unchanged.
__global__ __launch_bounds__(256) void table_kernel(
    const unsigned* __restrict__ hist, float* __restrict__ tabg)
{
    __shared__ float    cdf[6 * BINS];
    __shared__ unsigned wsum[4];

    const int t    = threadIdx.x;
    const int lane = t & 63;
    const int wid  = t >> 6;

    for (int ch = 0; ch < 6; ch++) {
        unsigned x = 0;
#pragma unroll
        for (int cp = 0; cp < NCOPY; cp++) x += hist[cp * (6 * BINS) + ch * BINS + t];
#pragma unroll
        for (int d = 1; d < 64; d <<= 1) {
            const unsigned y = __shfl_up(x, d, 64);
            if (lane >= d) x += y;
        }
        if (lane == 63) wsum[wid] = x;
        __syncthreads();
        unsigned prefix = 0;
        for (int w = 0; w < wid; w++) prefix += wsum[w];
        x += prefix;
        cdf[ch * BINS + t] = (float)x / 2000000.0f;
        __syncthreads();
    }
    for (int c = 0; c < 3; c++) {
        float o;
        if (t == 0)             o = 0.0f;
        else if (t == BINS - 1) o = 255.0f;
        else {
            const float v = cdf[c * BINS + t];
            const float* arr = cdf + (3 + c) * BINS;
            int lo = 0, hi = 256;
            while (lo < hi) { const int mid = (lo + hi) >> 1; if (arr[mid] < v) lo = mid + 1; else hi = mid; }
            const int J0 = ((lo > 1) ? lo : 1) - 1;
            int lo2 = 0, hi2 = 256;
            while (lo2 < hi2) { const int mid = (lo2 + hi2) >> 1; if (arr[mid] <= v) lo2 = mid + 1; else hi2 = mid; }
            const int J1 = ((lo2 - 1) < 254 ? (lo2 - 1) : 254);
            const bool found = (lo2 >= 1) && (J0 <= J1);
            o = found ? (float)(J0 + 1) : (float)t;
        }
        tabg[c * BINS + t] = o;
    }
}

// Node 6: streaming loss (validated logic; flags byte array).
__global__ __launch_bounds__(256) void tabloss_kernel(
    const float* __restrict__ inp, const float* __restrict__ ref,
    const float* __restrict__ msrc, const float* __restrict__ tabg,
    const unsigned char* __restrict__ flags, double* __restrict__ partials)
{
    __shared__ float  tab[3 * BINS];
    __shared__ double red[256];

    const int t = threadIdx.x;
    for (int k = t; k < 3 * BINS; k += 256) tab[k] = tabg[k];
    __syncthreads();

    double local = 0.0;
    const int stride = gridDim.x * 256;
    for (int g = blockIdx.x * 256 + t; g < HH / 4; g += stride) {
        const int p = g * 4;
        const float4 mv = *(const float4*)(msrc + p);
        const uchar4 fw = *(const uchar4*)(flags + p);
        const unsigned samp[4] = {fw.x, fw.y, fw.z, fw.w};
        const float m[4] = {mv.x, mv.y, mv.z, mv.w};
#pragma unroll
        for (int c = 0; c < 3; c++) {
            const float4 rv = *(const float4*)(ref + c * HH + p);
            const float4 iv = *(const float4*)(inp + c * HH + p);
            const float r[4] = {rv.x, rv.y, rv.z, rv.w};
            const float x4[4] = {iv.x, iv.y, iv.z, iv.w};
            float s = 0.0f;
#pragma unroll
            for (int k = 0; k < 4; k++) {
                const float mm = m[k];
                const float refm = ((r[k] + 1.0f) * 0.5f) * 255.0f * mm;
                const float inpm = ((x4[k] + 1.0f) * 0.5f) * 255.0f * mm;
                float matchv;
                if (samp[k]) {
                    const int bidx = (int)fminf(fmaxf(refm, 0.0f), 255.0f);
                    matchv = tab[c * BINS + bidx];
                } else {
                    matchv = refm;
                }
                const float dd = inpm - matchv * mm;
                s += dd * dd;
            }
            local += (double)s;
        }
    }
    red[t] = local;
    __syncthreads();
    for (int s2 = 128; s2 > 0; s2 >>= 1) {
        if (t < s2) red[t] += red[t + s2];
        __syncthreads();
    }
    if (t == 0) partials[blockIdx.x] = red[0];
}

// Node 7: single-block finalize.
__global__ __launch_bounds__(256) void finalize_kernel(
    const double* __restrict__ partials, float* __restrict__ out)
{
    const int t = threadIdx.x;
    double s = 0.0;
    for (int k = t; k < TL_BLOCKS; k += 256) s += partials[k];
    __shared__ double red[256];
    red[t] = s;
    __syncthreads();
    for (int s2 = 128; s2 > 0; s2 >>= 1) {
        if (t < s2) red[t] += red[t + s2];
        __syncthreads();
    }
    if (t == 0) out[0] = (float)(red[0] / (double)(3 * HH));
}

extern "C" void kernel_launch(void* const* d_in, const int* in_sizes, int n_in,
                              void* d_out, int out_size, void* d_ws, size_t ws_size,
                              hipStream_t stream)
{
    const float* input_data  = (const float*)d_in[0];
    const float* target_data = (const float*)d_in[1];
    const float* mask_src    = (const float*)d_in[2];
    const float* mask_tar    = (const float*)d_in[3];
    const int*   i0          = (const int*)d_in[4];
    const int*   i1          = (const int*)d_in[5];
    const int*   i2          = (const int*)d_in[6];
    const int*   i3          = (const int*)d_in[7];
    const float* ref_data    = (const float*)d_in[8];
    float* out = (float*)d_out;

    char* ws = (char*)d_ws;
    double*         partials = (double*)(ws + PART_OFF);
    float*          tabg     = (float*)(ws + TAB_OFF);
    unsigned*       Wg       = (unsigned*)(ws + WGL_OFF);
    unsigned*       hist     = (unsigned*)(ws + HIST_OFF);
    unsigned short* cnt_d    = (unsigned short*)(ws + CNT_D_OFF);
    unsigned short* cnt_r    = (unsigned short*)(ws + CNT_R_OFF);
    unsigned*       off_d    = (unsigned*)(ws + OFF_D_OFF);
    unsigned*       off_r    = (unsigned*)(ws + OFF_R_OFF);
    unsigned*       flags32  = (unsigned*)(ws + FLAGS_OFF);
    unsigned char*  flags    = (unsigned char*)(ws + FLAGS_OFF);
    unsigned short* sorted_d = (unsigned short*)(ws + SORT_D_OFF);
    unsigned short* sorted_r = (unsigned short*)(ws + SORT_R_OFF);

    prep_kernel<<<2048, 256, 0, stream>>>(i0, i1, i2, i3, hist, flags32, cnt_d, cnt_r);
    off_kernel<<<1, 1024, 0, stream>>>(cnt_d, cnt_r, off_d, off_r, Wg);
    place_kernel<<<NCHUNK, 256, 0, stream>>>(i0, i1, i2, i3, off_d, off_r, sorted_d, sorted_r);
    whist_kernel<<<2048, 256, 0, stream>>>(ref_data, target_data, mask_src, mask_tar,
                                           sorted_d, sorted_r, Wg, flags, hist);
    table_kernel<<<1, 256, 0, stream>>>(hist, tabg);
    tabloss_kernel<<<TL_BLOCKS, 256, 0, stream>>>(input_data, ref_data, mask_src, tabg,
                                                  flags, partials);
    finalize_kernel<<<1, 256, 0, stream>>>(partials, out);
}

// Round 11
// 354.604 us; speedup vs baseline: 1.1148x; 1.1148x over previous
//
#include <hip/hip_runtime.h>

#define HDIM 2048
#define HH (HDIM * HDIM)          // 4,194,304
#define NIDX 2000000
#define BINS 256
#define NCOPY 16
#define TL_BLOCKS 2048            // tabloss grid (partials count)
#define WH_BLOCKS 2048
#define NWIN 5                    // windows via w=(pd*5)>>22: 3.2MB packed each (<4MB XCD L2)

// workspace layout (bytes) — ~52.1 MB (R8-proven size)
#define PART_OFF     0                      // double partials[TL_BLOCKS] = 16 KB
#define TAB_OFF      16384                  // float tab[3*BINS] = 3 KB
#define HIST_OFF     20480                  // uint hist[NCOPY][6][256] = 96 KB
#define FLAGS_OFF    131072                 // uchar flags[HH] = 4 MB
#define PD_OFF       4325376                // int pd[NIDX] = 8 MB
#define PR_OFF       12713984               // int pr[NIDX] = 8 MB
#define PACKED_D_OFF 21102592               // uint packed_d[HH] = 16 MB
#define PACKED_R_OFF 37879808               // uint packed_r[HH] = 16 MB (ends ~52.1 MB)
#define MEMSET_BYTES (4325376 - 20480)      // hist + pad + flags

// Node 1: pack 3 channel bins (mask folded: v*0 -> bin 0) into bits 0..23 of
// one uint per pixel + flatten sample indices to pd/pr. Zeroing moved to
// hipMemsetAsync (R11).
__global__ __launch_bounds__(256) void pack_kernel(
    const float* __restrict__ ref, const float* __restrict__ tgt,
    const float* __restrict__ msrc, const float* __restrict__ mtar,
    const int* __restrict__ i0, const int* __restrict__ i1,
    const int* __restrict__ i2, const int* __restrict__ i3,
    unsigned* __restrict__ packed_d, unsigned* __restrict__ packed_r,
    int* __restrict__ pdArr, int* __restrict__ prArr)
{
    const int gtid = blockIdx.x * 256 + threadIdx.x;
    const int stride = gridDim.x * 256;

    // flatten indices (streaming): pd = i0*2048 + i1, pr = i2*2048 + i3
    for (int s = gtid; s < NIDX / 4; s += stride) {
        const int4 a = ((const int4*)i0)[s];
        const int4 b = ((const int4*)i1)[s];
        const int4 c = ((const int4*)i2)[s];
        const int4 d = ((const int4*)i3)[s];
        ((int4*)pdArr)[s] = make_int4(a.x * HDIM + b.x, a.y * HDIM + b.y,
                                      a.z * HDIM + b.z, a.w * HDIM + b.w);
        ((int4*)prArr)[s] = make_int4(c.x * HDIM + d.x, c.y * HDIM + d.y,
                                      c.z * HDIM + d.z, c.w * HDIM + d.w);
    }

    for (int g = gtid; g < HH / 4; g += stride) {
        const int p = g * 4;
        const float4 ms4 = *(const float4*)(msrc + p);
        const float4 mt4 = *(const float4*)(mtar + p);
        const float ms[4] = {ms4.x, ms4.y, ms4.z, ms4.w};
        const float mt[4] = {mt4.x, mt4.y, mt4.z, mt4.w};
        unsigned od[4] = {0, 0, 0, 0}, orr[4] = {0, 0, 0, 0};
#pragma unroll
        for (int c = 0; c < 3; c++) {
            const float4 rv = *(const float4*)(ref + c * HH + p);
            const float4 tv = *(const float4*)(tgt + c * HH + p);
            const float r[4] = {rv.x, rv.y, rv.z, rv.w};
            const float tt[4] = {tv.x, tv.y, tv.z, tv.w};
#pragma unroll
            for (int k = 0; k < 4; k++) {
                // reference op order: ((x+1)*0.5)*255, then * mask
                const float vd = ((r[k] + 1.0f) * 0.5f) * 255.0f * ms[k];
                const float vr = ((tt[k] + 1.0f) * 0.5f) * 255.0f * mt[k];
                const unsigned bd = (unsigned)(int)fminf(fmaxf(floorf(vd), 0.0f), 255.0f);
                const unsigned br = (unsigned)(int)fminf(fmaxf(floorf(vr), 0.0f), 255.0f);
                od[k]  |= bd << (8 * c);
                orr[k] |= br << (8 * c);
            }
        }
        *(uint4*)(packed_d + p) = make_uint4(od[0], od[1], od[2], od[3]);
        *(uint4*)(packed_r + p) = make_uint4(orr[0], orr[1], orr[2], orr[3]);
    }
}

// Node 2: WINDOWED gather histogram (R8-proven structure; R7/R8 counters show
// in-window gathers are L2 hits). R11: NWIN=5 multiply-windows — restream
// 80MB (was 128) at 3.2MB packed window (<4MB XCD L2). Bin-0 in registers
// (LDS same-address hotspot); flags = idempotent window-local byte stores;
// flush = 16-copy burst atomics (hot-region merge, R3 evidence).
__global__ __launch_bounds__(256) void whist_kernel(
    const unsigned* __restrict__ packed_d, const unsigned* __restrict__ packed_r,
    const int* __restrict__ pdArr, const int* __restrict__ prArr,
    unsigned char* __restrict__ flags, unsigned* __restrict__ hist)
{
    __shared__ unsigned lhist[6 * BINS];
    for (int k = threadIdx.x; k < 6 * BINS; k += 256) lhist[k] = 0;
    __syncthreads();

    unsigned z0 = 0, z1 = 0, z2 = 0, z3 = 0, z4 = 0, z5 = 0;
    const int stride = gridDim.x * 256;

    // ---- d side: ref-image histogram + sampled flags ----
    for (int w = 0; w < NWIN; w++) {
        for (int q = blockIdx.x * 256 + threadIdx.x; q < NIDX / 4; q += stride) {
            const int4 pv = ((const int4*)pdArr)[q];
            const int pd[4] = {pv.x, pv.y, pv.z, pv.w};
#pragma unroll
            for (int k = 0; k < 4; k++) {
                if ((int)(((unsigned)pd[k] * 5u) >> 22) == w) {
                    const unsigned wd = packed_d[pd[k]];
                    flags[pd[k]] = 1;                // in-window, benign idempotent race
                    const unsigned d0 =  wd        & 255u;
                    const unsigned d1 = (wd >> 8 ) & 255u;
                    const unsigned d2 = (wd >> 16) & 255u;
                    if (d0) atomicAdd(&lhist[           d0], 1u); else z0++;
                    if (d1) atomicAdd(&lhist[1 * BINS + d1], 1u); else z1++;
                    if (d2) atomicAdd(&lhist[2 * BINS + d2], 1u); else z2++;
                }
            }
        }
    }
    // ---- r side: target-image histogram ----
    for (int w = 0; w < NWIN; w++) {
        for (int q = blockIdx.x * 256 + threadIdx.x; q < NIDX / 4; q += stride) {
            const int4 pv = ((const int4*)prArr)[q];
            const int pr[4] = {pv.x, pv.y, pv.z, pv.w};
#pragma unroll
            for (int k = 0; k < 4; k++) {
                if ((int)(((unsigned)pr[k] * 5u) >> 22) == w) {
                    const unsigned wr = packed_r[pr[k]];
                    const unsigned r0 =  wr        & 255u;
                    const unsigned r1 = (wr >> 8 ) & 255u;
                    const unsigned r2 = (wr >> 16) & 255u;
                    if (r0) atomicAdd(&lhist[3 * BINS + r0], 1u); else z3++;
                    if (r1) atomicAdd(&lhist[4 * BINS + r1], 1u); else z4++;
                    if (r2) atomicAdd(&lhist[5 * BINS + r2], 1u); else z5++;
                }
            }
        }
    }

    if (z0) atomicAdd(&lhist[0 * BINS], z0);
    if (z1) atomicAdd(&lhist[1 * BINS], z1);
    if (z2) atomicAdd(&lhist[2 * BINS], z2);
    if (z3) atomicAdd(&lhist[3 * BINS], z3);
    if (z4) atomicAdd(&lhist[4 * BINS], z4);
    if (z5) atomicAdd(&lhist[5 * BINS], z5);
    __syncthreads();
    unsigned* h = hist + (blockIdx.x & (NCOPY - 1)) * (6 * BINS);
    for (int k = threadIdx.x; k < 6 * BINS; k += 256) {
        const unsigned v = lhist[k];
        if (v) atomicAdd(&h[k], v);
    }
}

// Node 3: transfer table computed ONCE (1 block). Validated logic: exact int
// scan -> single-rounding divide -> bsearch. Sums the 16 hist copies.
__global__ __launch_bounds__(256) void table_kernel(
    const unsigned* __restrict__ hist, float* __restrict__ tabg)
{
    __shared__ float    cdf[6 * BINS];
    __shared__ unsigned wsum[4];

    const int t    = threadIdx.x;
    const int lane = t & 63;
    const int wid  = t >> 6;

    for (int ch = 0; ch < 6; ch++) {
        unsigned x = 0;
#pragma unroll
        for (int cp = 0; cp < NCOPY; cp++) x += hist[cp * (6 * BINS) + ch * BINS + t];
#pragma unroll
        for (int d = 1; d < 64; d <<= 1) {
            const unsigned y = __shfl_up(x, d, 64);
            if (lane >= d) x += y;
        }
        if (lane == 63) wsum[wid] = x;
        __syncthreads();
        unsigned prefix = 0;
        for (int w = 0; w < wid; w++) prefix += wsum[w];
        x += prefix;
        cdf[ch * BINS + t] = (float)x / 2000000.0f;   // exact int < 2^24, single rounding
        __syncthreads();
    }
    for (int c = 0; c < 3; c++) {
        float o;
        if (t == 0)             o = 0.0f;
        else if (t == BINS - 1) o = 255.0f;
        else {
            const float v = cdf[c * BINS + t];
            const float* arr = cdf + (3 + c) * BINS;
            int lo = 0, hi = 256;   // lower_bound: first k with arr[k] >= v
            while (lo < hi) { const int mid = (lo + hi) >> 1; if (arr[mid] < v) lo = mid + 1; else hi = mid; }
            const int J0 = ((lo > 1) ? lo : 1) - 1;
            int lo2 = 0, hi2 = 256; // upper_bound: first k with arr[k] > v
            while (lo2 < hi2) { const int mid = (lo2 + hi2) >> 1; if (arr[mid] <= v) lo2 = mid + 1; else hi2 = mid; }
            const int J1 = ((lo2 - 1) < 254 ? (lo2 - 1) : 254);
            const bool found = (lo2 >= 1) && (J0 <= J1);
            o = found ? (float)(J0 + 1) : (float)t;
        }
        tabg[c * BINS + t] = o;
    }
}

// Node 4: streaming loss. Sampled flag from the 4MB byte array (coalesced
// uchar4 loads). Plain per-block partial store; stream-order visibility.
__global__ __launch_bounds__(256) void tabloss_kernel(
    const float* __restrict__ inp, const float* __restrict__ ref,
    const float* __restrict__ msrc, const float* __restrict__ tabg,
    const unsigned char* __restrict__ flags, double* __restrict__ partials)
{
    __shared__ float  tab[3 * BINS];
    __shared__ double red[256];

    const int t = threadIdx.x;
    for (int k = t; k < 3 * BINS; k += 256) tab[k] = tabg[k];
    __syncthreads();

    double local = 0.0;
    const int stride = gridDim.x * 256;
    for (int g = blockIdx.x * 256 + t; g < HH / 4; g += stride) {
        const int p = g * 4;
        const float4 mv = *(const float4*)(msrc + p);
        const uchar4 fw = *(const uchar4*)(flags + p);
        const unsigned samp[4] = {fw.x, fw.y, fw.z, fw.w};
        const float m[4] = {mv.x, mv.y, mv.z, mv.w};
#pragma unroll
        for (int c = 0; c < 3; c++) {
            const float4 rv = *(const float4*)(ref + c * HH + p);
            const float4 iv = *(const float4*)(inp + c * HH + p);
            const float r[4] = {rv.x, rv.y, rv.z, rv.w};
            const float x4[4] = {iv.x, iv.y, iv.z, iv.w};
            float s = 0.0f;
#pragma unroll
            for (int k = 0; k < 4; k++) {
                const float mm = m[k];
                const float refm = ((r[k] + 1.0f) * 0.5f) * 255.0f * mm;   // ref_masked
                const float inpm = ((x4[k] + 1.0f) * 0.5f) * 255.0f * mm;  // input_masked
                float matchv;
                if (samp[k]) {
                    const int bidx = (int)fminf(fmaxf(refm, 0.0f), 255.0f); // clip-then-trunc
                    matchv = tab[c * BINS + bidx];
                } else {
                    matchv = refm;
                }
                const float dd = inpm - matchv * mm;
                s += dd * dd;
            }
            local += (double)s;
        }
    }
    red[t] = local;
    __syncthreads();
    for (int s2 = 128; s2 > 0; s2 >>= 1) {
        if (t < s2) red[t] += red[t + s2];
        __syncthreads();
    }
    if (t == 0) partials[blockIdx.x] = red[0];
}

// Node 5: single-block finalize (plain loads; stream order guarantees visibility).
__global__ __launch_bounds__(256) void finalize_kernel(
    const double* __restrict__ partials, float* __restrict__ out)
{
    const int t = threadIdx.x;
    double s = 0.0;
    for (int k = t; k < TL_BLOCKS; k += 256) s += partials[k];
    __shared__ double red[256];
    red[t] = s;
    __syncthreads();
    for (int s2 = 128; s2 > 0; s2 >>= 1) {
        if (t < s2) red[t] += red[t + s2];
        __syncthreads();
    }
    if (t == 0) out[0] = (float)(red[0] / (double)(3 * HH));
}

extern "C" void kernel_launch(void* const* d_in, const int* in_sizes, int n_in,
                              void* d_out, int out_size, void* d_ws, size_t ws_size,
                              hipStream_t stream)
{
    const float* input_data  = (const float*)d_in[0];
    const float* target_data = (const float*)d_in[1];
    const float* mask_src    = (const float*)d_in[2];
    const float* mask_tar    = (const float*)d_in[3];
    const int*   i0          = (const int*)d_in[4];
    const int*   i1          = (const int*)d_in[5];
    const int*   i2          = (const int*)d_in[6];
    const int*   i3          = (const int*)d_in[7];
    const float* ref_data    = (const float*)d_in[8];
    float* out = (float*)d_out;

    char* ws = (char*)d_ws;
    double*        partials = (double*)(ws + PART_OFF);
    float*         tabg     = (float*)(ws + TAB_OFF);
    unsigned*      hist     = (unsigned*)(ws + HIST_OFF);
    unsigned char* flags    = (unsigned char*)(ws + FLAGS_OFF);
    int*           pdArr    = (int*)(ws + PD_OFF);
    int*           prArr    = (int*)(ws + PR_OFF);
    unsigned*      packed_d = (unsigned*)(ws + PACKED_D_OFF);
    unsigned*      packed_r = (unsigned*)(ws + PACKED_R_OFF);

    hipMemsetAsync(ws + HIST_OFF, 0, MEMSET_BYTES, stream);
    pack_kernel<<<2048, 256, 0, stream>>>(ref_data, target_data, mask_src, mask_tar,
                                          i0, i1, i2, i3,
                                          packed_d, packed_r, pdArr, prArr);
    whist_kernel<<<WH_BLOCKS, 256, 0, stream>>>(packed_d, packed_r, pdArr, prArr,
                                                flags, hist);
    table_kernel<<<1, 256, 0, stream>>>(hist, tabg);
    tabloss_kernel<<<TL_BLOCKS, 256, 0, stream>>>(input_data, ref_data, mask_src, tabg,
                                                  flags, partials);
    finalize_kernel<<<1, 256, 0, stream>>>(partials, out);
}

// Round 12
// 342.817 us; speedup vs baseline: 1.1532x; 1.0344x over previous
//
#include <hip/hip_runtime.h>

#define HDIM 2048
#define HH (HDIM * HDIM)          // 4,194,304 = 2^22
#define NIDX 2000000
#define BINS 256
#define NCOPY 16
#define TL_BLOCKS 2048
#define NCHUNK 1000               // sort chunks: 2000 samples (500 int4) each
#define CH_I4 500
#define NWIN 128                  // window = pd>>15: 32K pixels

// workspace layout (bytes) — ~30 MB
#define PART_OFF   0                        // double partials[2048] = 16 KB
#define TAB_OFF    16384                    // float tab[3*BINS]
#define WGL_OFF    20480                    // uint Wg[2][129]
#define HIST_OFF   24576                    // uint hist[16][6][256] = 96 KB (memset)
#define CNT_D_OFF  131072                   // ushort cnt_d[1000][128] = 256 KB
#define CNT_R_OFF  393216
#define OFF_D_OFF  655360                   // uint off_d[1000][128] = 512 KB
#define OFF_R_OFF  1179648
#define FLAGS_OFF  2097152                  // uchar flags[HH] = 4 MB (whist2 writes all)
#define SORT_D_OFF 6291456                  // ushort sorted_d[NIDX] = 4 MB
#define SORT_R_OFF 10485760                 // ushort sorted_r[NIDX] = 4 MB
#define PD_OFF     14680064                 // int pd[NIDX] = 8 MB
#define PR_OFF     23068672                 // int pr[NIDX] = 8 MB (ends 30 MB)

// Node 1: chunk-aligned flatten + per-chunk window counts (LDS only — R6
// lesson: no global allocator atomics). Block b owns samples [b*2000,(b+1)*2000).
__global__ __launch_bounds__(256) void flat_kernel(
    const int* __restrict__ i0, const int* __restrict__ i1,
    const int* __restrict__ i2, const int* __restrict__ i3,
    int* __restrict__ pdArr, int* __restrict__ prArr,
    unsigned short* __restrict__ cnt_d, unsigned short* __restrict__ cnt_r)
{
    __shared__ unsigned cntd[NWIN], cntr[NWIN];
    const int b = blockIdx.x, t = threadIdx.x;
    for (int k = t; k < NWIN; k += 256) { cntd[k] = 0; cntr[k] = 0; }
    __syncthreads();

    for (int i = t; i < CH_I4; i += 256) {
        const int q = b * CH_I4 + i;
        const int4 a  = ((const int4*)i0)[q];
        const int4 bb = ((const int4*)i1)[q];
        const int4 c  = ((const int4*)i2)[q];
        const int4 d  = ((const int4*)i3)[q];
        const int4 pd4 = make_int4(a.x * HDIM + bb.x, a.y * HDIM + bb.y,
                                   a.z * HDIM + bb.z, a.w * HDIM + bb.w);
        const int4 pr4 = make_int4(c.x * HDIM + d.x, c.y * HDIM + d.y,
                                   c.z * HDIM + d.z, c.w * HDIM + d.w);
        ((int4*)pdArr)[q] = pd4;
        ((int4*)prArr)[q] = pr4;
        atomicAdd(&cntd[pd4.x >> 15], 1u); atomicAdd(&cntd[pd4.y >> 15], 1u);
        atomicAdd(&cntd[pd4.z >> 15], 1u); atomicAdd(&cntd[pd4.w >> 15], 1u);
        atomicAdd(&cntr[pr4.x >> 15], 1u); atomicAdd(&cntr[pr4.y >> 15], 1u);
        atomicAdd(&cntr[pr4.z >> 15], 1u); atomicAdd(&cntr[pr4.w >> 15], 1u);
    }
    __syncthreads();
    for (int k = t; k < NWIN; k += 256) {
        cnt_d[b * NWIN + k] = (unsigned short)cntd[k];
        cnt_r[b * NWIN + k] = (unsigned short)cntr[k];
    }
}

// Node 2: exact deterministic offsets (1 block, integer prefix sums).
__global__ __launch_bounds__(1024) void off_kernel(
    const unsigned short* __restrict__ cnt_d, const unsigned short* __restrict__ cnt_r,
    unsigned* __restrict__ off_d, unsigned* __restrict__ off_r, unsigned* __restrict__ Wg)
{
    __shared__ unsigned psum[8][NWIN], segbase[8][NWIN], wtot[NWIN], Wl[NWIN + 1];
    const int t = threadIdx.x;
    const int w = t & (NWIN - 1), seg = t >> 7;      // 8 segs x 125 chunks

    for (int side = 0; side < 2; side++) {
        const unsigned short* cnt = side ? cnt_r : cnt_d;
        unsigned* off = side ? off_r : off_d;
        unsigned s = 0;
        for (int b = seg * 125; b < seg * 125 + 125; b++) s += cnt[b * NWIN + w];
        psum[seg][w] = s;
        __syncthreads();
        if (t < NWIN) {
            unsigned run = 0;
            for (int sg = 0; sg < 8; sg++) { segbase[sg][t] = run; run += psum[sg][t]; }
            wtot[t] = run;
        }
        __syncthreads();
        if (t == 0) {
            unsigned run = 0;
            for (int w2 = 0; w2 < NWIN; w2++) { Wl[w2] = run; run += wtot[w2]; }
            Wl[NWIN] = run;                           // = NIDX
        }
        __syncthreads();
        unsigned run2 = Wl[w] + segbase[seg][w];
        for (int b = seg * 125; b < seg * 125 + 125; b++) {
            off[b * NWIN + w] = run2;
            run2 += cnt[b * NWIN + w];
        }
        if (t < NWIN + 1) Wg[side * (NWIN + 1) + t] = Wl[t];
        __syncthreads();
    }
}

// Node 3: place samples into exact sorted slots (LDS cursors; every slot
// written once; within-run order benign for order-independent counting).
__global__ __launch_bounds__(256) void place_kernel(
    const int* __restrict__ pdArr, const int* __restrict__ prArr,
    const unsigned* __restrict__ off_d, const unsigned* __restrict__ off_r,
    unsigned short* __restrict__ sorted_d, unsigned short* __restrict__ sorted_r)
{
    __shared__ unsigned cur[NWIN];
    const int b = blockIdx.x, t = threadIdx.x;

    for (int k = t; k < NWIN; k += 256) cur[k] = off_d[b * NWIN + k];
    __syncthreads();
    for (int i = t; i < CH_I4; i += 256) {
        const int4 p4 = ((const int4*)pdArr)[b * CH_I4 + i];
        const int pd[4] = {p4.x, p4.y, p4.z, p4.w};
#pragma unroll
        for (int k = 0; k < 4; k++) {
            const unsigned pos = atomicAdd(&cur[pd[k] >> 15], 1u);
            sorted_d[pos] = (unsigned short)(pd[k] & 32767);
        }
    }
    __syncthreads();
    for (int k = t; k < NWIN; k += 256) cur[k] = off_r[b * NWIN + k];
    __syncthreads();
    for (int i = t; i < CH_I4; i += 256) {
        const int4 p4 = ((const int4*)prArr)[b * CH_I4 + i];
        const int pr[4] = {p4.x, p4.y, p4.z, p4.w};
#pragma unroll
        for (int k = 0; k < 4; k++) {
            const unsigned pos = atomicAdd(&cur[pr[k] >> 15], 1u);
            sorted_r[pos] = (unsigned short)(pr[k] & 32767);
        }
    }
}

// Node 4: LDS COUNT-MAP histogram — zero random access. Block (win, half,
// side): read window's sorted entries (~8KB), build u8 multiplicity map in
// 32KB LDS (sub-word atomicAdd; max multiplicity ~10 << 255), then SWEEP the
// half-window's floats SEQUENTIALLY (ref/tgt + masks direct — packed arrays
// and the 208MB pack kernel deleted), weighted-binning with validated math.
// d-side writes flags for every pixel (replaces memset). Bin-0 in registers.
__global__ __launch_bounds__(256) void whist2_kernel(
    const float* __restrict__ ref, const float* __restrict__ tgt,
    const float* __restrict__ msrc, const float* __restrict__ mtar,
    const unsigned short* __restrict__ sorted_d, const unsigned short* __restrict__ sorted_r,
    const unsigned* __restrict__ Wg,
    unsigned char* __restrict__ flags, unsigned* __restrict__ hist)
{
    __shared__ unsigned cnt32[8192];        // u8[32768] count map, 32 KB
    __shared__ unsigned lhist[3 * BINS];    // this side's 3 channels

    const int b = blockIdx.x, t = threadIdx.x;
    const int side = b & 1, half = (b >> 1) & 1, win = b >> 2;

    for (int k = t; k < 8192; k += 256) cnt32[k] = 0;
    for (int k = t; k < 3 * BINS; k += 256) lhist[k] = 0;
    __syncthreads();

    const unsigned e0 = Wg[side * (NWIN + 1) + win];
    const unsigned e1 = Wg[side * (NWIN + 1) + win + 1];
    const unsigned short* se = side ? sorted_r : sorted_d;
    for (unsigned e = e0 + t; e < e1; e += 256) {
        const unsigned lo = se[e];
        atomicAdd(&cnt32[lo >> 2], 1u << ((lo & 3) * 8));
    }
    __syncthreads();

    const float* img = side ? tgt : ref;
    const float* msk = side ? mtar : msrc;
    const int P0 = (win << 15) + half * 16384;    // half-window base pixel
    unsigned z0 = 0, z1 = 0, z2 = 0;

    for (int j = t; j < 4096; j += 256) {         // 4096 words x 4 pixels
        const unsigned cw = cnt32[half * 4096 + j];
        const int p = P0 + j * 4;
        if (side == 0) {
            const uchar4 f = make_uchar4((cw & 255u) ? 1 : 0, ((cw >> 8) & 255u) ? 1 : 0,
                                         ((cw >> 16) & 255u) ? 1 : 0, (cw >> 24) ? 1 : 0);
            *(uchar4*)(flags + p) = f;
        }
        if (cw == 0) continue;
        const float4 m4 = *(const float4*)(msk + p);
        const float4 v0 = *(const float4*)(img + p);
        const float4 v1 = *(const float4*)(img + HH + p);
        const float4 v2 = *(const float4*)(img + 2 * HH + p);
        const float m[4]  = {m4.x, m4.y, m4.z, m4.w};
        const float a0[4] = {v0.x, v0.y, v0.z, v0.w};
        const float a1[4] = {v1.x, v1.y, v1.z, v1.w};
        const float a2[4] = {v2.x, v2.y, v2.z, v2.w};
#pragma unroll
        for (int k = 0; k < 4; k++) {
            const unsigned c = (cw >> (k * 8)) & 255u;
            if (!c) continue;
            const float mm = m[k];
            // validated reference op order: ((x+1)*0.5)*255, then * mask
            const float f0 = ((a0[k] + 1.0f) * 0.5f) * 255.0f * mm;
            const float f1 = ((a1[k] + 1.0f) * 0.5f) * 255.0f * mm;
            const float f2 = ((a2[k] + 1.0f) * 0.5f) * 255.0f * mm;
            const unsigned b0 = (unsigned)(int)fminf(fmaxf(floorf(f0), 0.0f), 255.0f);
            const unsigned b1 = (unsigned)(int)fminf(fmaxf(floorf(f1), 0.0f), 255.0f);
            const unsigned b2 = (unsigned)(int)fminf(fmaxf(floorf(f2), 0.0f), 255.0f);
            if (b0) atomicAdd(&lhist[           b0], c); else z0 += c;
            if (b1) atomicAdd(&lhist[1 * BINS + b1], c); else z1 += c;
            if (b2) atomicAdd(&lhist[2 * BINS + b2], c); else z2 += c;
        }
    }
    if (z0) atomicAdd(&lhist[0 * BINS], z0);
    if (z1) atomicAdd(&lhist[1 * BINS], z1);
    if (z2) atomicAdd(&lhist[2 * BINS], z2);
    __syncthreads();
    unsigned* h = hist + (b & (NCOPY - 1)) * (6 * BINS) + side * (3 * BINS);
    for (int k = t; k < 3 * BINS; k += 256) {
        const unsigned v = lhist[k];
        if (v) atomicAdd(&h[k], v);
    }
}

// Node 5: transfer table (1 block). Validated logic unchanged.
__global__ __launch_bounds__(256) void table_kernel(
    const unsigned* __restrict__ hist, float* __restrict__ tabg)
{
    __shared__ float    cdf[6 * BINS];
    __shared__ unsigned wsum[4];

    const int t    = threadIdx.x;
    const int lane = t & 63;
    const int wid  = t >> 6;

    for (int ch = 0; ch < 6; ch++) {
        unsigned x = 0;
#pragma unroll
        for (int cp = 0; cp < NCOPY; cp++) x += hist[cp * (6 * BINS) + ch * BINS + t];
#pragma unroll
        for (int d = 1; d < 64; d <<= 1) {
            const unsigned y = __shfl_up(x, d, 64);
            if (lane >= d) x += y;
        }
        if (lane == 63) wsum[wid] = x;
        __syncthreads();
        unsigned prefix = 0;
        for (int w = 0; w < wid; w++) prefix += wsum[w];
        x += prefix;
        cdf[ch * BINS + t] = (float)x / 2000000.0f;   // exact int < 2^24, single rounding
        __syncthreads();
    }
    for (int c = 0; c < 3; c++) {
        float o;
        if (t == 0)             o = 0.0f;
        else if (t == BINS - 1) o = 255.0f;
        else {
            const float v = cdf[c * BINS + t];
            const float* arr = cdf + (3 + c) * BINS;
            int lo = 0, hi = 256;   // lower_bound
            while (lo < hi) { const int mid = (lo + hi) >> 1; if (arr[mid] < v) lo = mid + 1; else hi = mid; }
            const int J0 = ((lo > 1) ? lo : 1) - 1;
            int lo2 = 0, hi2 = 256; // upper_bound
            while (lo2 < hi2) { const int mid = (lo2 + hi2) >> 1; if (arr[mid] <= v) lo2 = mid + 1; else hi2 = mid; }
            const int J1 = ((lo2 - 1) < 254 ? (lo2 - 1) : 254);
            const bool found = (lo2 >= 1) && (J0 <= J1);
            o = found ? (float)(J0 + 1) : (float)t;
        }
        tabg[c * BINS + t] = o;
    }
}

// Node 6: streaming loss (validated logic; flags byte array).
__global__ __launch_bounds__(256) void tabloss_kernel(
    const float* __restrict__ inp, const float* __restrict__ ref,
    const float* __restrict__ msrc, const float* __restrict__ tabg,
    const unsigned char* __restrict__ flags, double* __restrict__ partials)
{
    __shared__ float  tab[3 * BINS];
    __shared__ double red[256];

    const int t = threadIdx.x;
    for (int k = t; k < 3 * BINS; k += 256) tab[k] = tabg[k];
    __syncthreads();

    double local = 0.0;
    const int stride = gridDim.x * 256;
    for (int g = blockIdx.x * 256 + t; g < HH / 4; g += stride) {
        const int p = g * 4;
        const float4 mv = *(const float4*)(msrc + p);
        const uchar4 fw = *(const uchar4*)(flags + p);
        const unsigned samp[4] = {fw.x, fw.y, fw.z, fw.w};
        const float m[4] = {mv.x, mv.y, mv.z, mv.w};
#pragma unroll
        for (int c = 0; c < 3; c++) {
            const float4 rv = *(const float4*)(ref + c * HH + p);
            const float4 iv = *(const float4*)(inp + c * HH + p);
            const float r[4] = {rv.x, rv.y, rv.z, rv.w};
            const float x4[4] = {iv.x, iv.y, iv.z, iv.w};
            float s = 0.0f;
#pragma unroll
            for (int k = 0; k < 4; k++) {
                const float mm = m[k];
                const float refm = ((r[k] + 1.0f) * 0.5f) * 255.0f * mm;
                const float inpm = ((x4[k] + 1.0f) * 0.5f) * 255.0f * mm;
                float matchv;
                if (samp[k]) {
                    const int bidx = (int)fminf(fmaxf(refm, 0.0f), 255.0f);
                    matchv = tab[c * BINS + bidx];
                } else {
                    matchv = refm;
                }
                const float dd = inpm - matchv * mm;
                s += dd * dd;
            }
            local += (double)s;
        }
    }
    red[t] = local;
    __syncthreads();
    for (int s2 = 128; s2 > 0; s2 >>= 1) {
        if (t < s2) red[t] += red[t + s2];
        __syncthreads();
    }
    if (t == 0) partials[blockIdx.x] = red[0];
}

// Node 7: single-block finalize.
__global__ __launch_bounds__(256) void finalize_kernel(
    const double* __restrict__ partials, float* __restrict__ out)
{
    const int t = threadIdx.x;
    double s = 0.0;
    for (int k = t; k < TL_BLOCKS; k += 256) s += partials[k];
    __shared__ double red[256];
    red[t] = s;
    __syncthreads();
    for (int s2 = 128; s2 > 0; s2 >>= 1) {
        if (t < s2) red[t] += red[t + s2];
        __syncthreads();
    }
    if (t == 0) out[0] = (float)(red[0] / (double)(3 * HH));
}

extern "C" void kernel_launch(void* const* d_in, const int* in_sizes, int n_in,
                              void* d_out, int out_size, void* d_ws, size_t ws_size,
                              hipStream_t stream)
{
    const float* input_data  = (const float*)d_in[0];
    const float* target_data = (const float*)d_in[1];
    const float* mask_src    = (const float*)d_in[2];
    const float* mask_tar    = (const float*)d_in[3];
    const int*   i0          = (const int*)d_in[4];
    const int*   i1          = (const int*)d_in[5];
    const int*   i2          = (const int*)d_in[6];
    const int*   i3          = (const int*)d_in[7];
    const float* ref_data    = (const float*)d_in[8];
    float* out = (float*)d_out;

    char* ws = (char*)d_ws;
    double*         partials = (double*)(ws + PART_OFF);
    float*          tabg     = (float*)(ws + TAB_OFF);
    unsigned*       Wg       = (unsigned*)(ws + WGL_OFF);
    unsigned*       hist     = (unsigned*)(ws + HIST_OFF);
    unsigned short* cnt_d    = (unsigned short*)(ws + CNT_D_OFF);
    unsigned short* cnt_r    = (unsigned short*)(ws + CNT_R_OFF);
    unsigned*       off_d    = (unsigned*)(ws + OFF_D_OFF);
    unsigned*       off_r    = (unsigned*)(ws + OFF_R_OFF);
    unsigned char*  flags    = (unsigned char*)(ws + FLAGS_OFF);
    unsigned short* sorted_d = (unsigned short*)(ws + SORT_D_OFF);
    unsigned short* sorted_r = (unsigned short*)(ws + SORT_R_OFF);
    int*            pdArr    = (int*)(ws + PD_OFF);
    int*            prArr    = (int*)(ws + PR_OFF);

    hipMemsetAsync(ws + HIST_OFF, 0, NCOPY * 6 * BINS * 4, stream);
    flat_kernel<<<NCHUNK, 256, 0, stream>>>(i0, i1, i2, i3, pdArr, prArr, cnt_d, cnt_r);
    off_kernel<<<1, 1024, 0, stream>>>(cnt_d, cnt_r, off_d, off_r, Wg);
    place_kernel<<<NCHUNK, 256, 0, stream>>>(pdArr, prArr, off_d, off_r, sorted_d, sorted_r);
    whist2_kernel<<<4 * NWIN, 256, 0, stream>>>(ref_data, target_data, mask_src, mask_tar,
                                                sorted_d, sorted_r, Wg, flags, hist);
    table_kernel<<<1, 256, 0, stream>>>(hist, tabg);
    tabloss_kernel<<<TL_BLOCKS, 256, 0, stream>>>(input_data, ref_data, mask_src, tabg,
                                                  flags, partials);
    finalize_kernel<<<1, 256, 0, stream>>>(partials, out);
}

// Round 13
// 341.577 us; speedup vs baseline: 1.1574x; 1.0036x over previous
//
#include <hip/hip_runtime.h>

#define HDIM 2048
#define HH (HDIM * HDIM)          // 4,194,304 = 2^22
#define NIDX 2000000
#define BINS 256
#define NCOPY 16
#define TL_BLOCKS 2048
#define NCHUNK 1000               // sort chunks: 2000 samples (500 int4) each
#define CH_I4 500
#define NWIN 128                  // window = pd>>15: 32K pixels

// workspace layout (bytes) — ~30 MB
#define PART_OFF   0                        // double partials[2048] = 16 KB
#define TAB_OFF    16384                    // float tab[3*BINS]
#define WGL_OFF    20480                    // uint Wg[2][129]
#define HIST_OFF   24576                    // uint hist[16][6][256] = 96 KB (memset)
#define CNT_D_OFF  131072                   // ushort cnt_d[1000][128] = 256 KB
#define CNT_R_OFF  393216
#define OFF_D_OFF  655360                   // uint off_d[1000][128] = 512 KB
#define OFF_R_OFF  1179648
#define FLAGS_OFF  2097152                  // uchar flags[HH] = 4 MB (whist2 writes all)
#define SORT_D_OFF 6291456                  // ushort sorted_d[NIDX] = 4 MB
#define SORT_R_OFF 10485760                 // ushort sorted_r[NIDX] = 4 MB
#define PD_OFF     14680064                 // int pd[NIDX] = 8 MB
#define PR_OFF     23068672                 // int pr[NIDX] = 8 MB (ends 30 MB)

// Node 1: chunk-aligned flatten + per-chunk window counts (LDS only — R6
// lesson: no global allocator atomics). Block b owns samples [b*2000,(b+1)*2000).
__global__ __launch_bounds__(256) void flat_kernel(
    const int* __restrict__ i0, const int* __restrict__ i1,
    const int* __restrict__ i2, const int* __restrict__ i3,
    int* __restrict__ pdArr, int* __restrict__ prArr,
    unsigned short* __restrict__ cnt_d, unsigned short* __restrict__ cnt_r)
{
    __shared__ unsigned cntd[NWIN], cntr[NWIN];
    const int b = blockIdx.x, t = threadIdx.x;
    for (int k = t; k < NWIN; k += 256) { cntd[k] = 0; cntr[k] = 0; }
    __syncthreads();

    for (int i = t; i < CH_I4; i += 256) {
        const int q = b * CH_I4 + i;
        const int4 a  = ((const int4*)i0)[q];
        const int4 bb = ((const int4*)i1)[q];
        const int4 c  = ((const int4*)i2)[q];
        const int4 d  = ((const int4*)i3)[q];
        const int4 pd4 = make_int4(a.x * HDIM + bb.x, a.y * HDIM + bb.y,
                                   a.z * HDIM + bb.z, a.w * HDIM + bb.w);
        const int4 pr4 = make_int4(c.x * HDIM + d.x, c.y * HDIM + d.y,
                                   c.z * HDIM + d.z, c.w * HDIM + d.w);
        ((int4*)pdArr)[q] = pd4;
        ((int4*)prArr)[q] = pr4;
        atomicAdd(&cntd[pd4.x >> 15], 1u); atomicAdd(&cntd[pd4.y >> 15], 1u);
        atomicAdd(&cntd[pd4.z >> 15], 1u); atomicAdd(&cntd[pd4.w >> 15], 1u);
        atomicAdd(&cntr[pr4.x >> 15], 1u); atomicAdd(&cntr[pr4.y >> 15], 1u);
        atomicAdd(&cntr[pr4.z >> 15], 1u); atomicAdd(&cntr[pr4.w >> 15], 1u);
    }
    __syncthreads();
    for (int k = t; k < NWIN; k += 256) {
        cnt_d[b * NWIN + k] = (unsigned short)cntd[k];
        cnt_r[b * NWIN + k] = (unsigned short)cntr[k];
    }
}

// Node 2: exact deterministic offsets (1 block, integer prefix sums).
__global__ __launch_bounds__(1024) void off_kernel(
    const unsigned short* __restrict__ cnt_d, const unsigned short* __restrict__ cnt_r,
    unsigned* __restrict__ off_d, unsigned* __restrict__ off_r, unsigned* __restrict__ Wg)
{
    __shared__ unsigned psum[8][NWIN], segbase[8][NWIN], wtot[NWIN], Wl[NWIN + 1];
    const int t = threadIdx.x;
    const int w = t & (NWIN - 1), seg = t >> 7;      // 8 segs x 125 chunks

    for (int side = 0; side < 2; side++) {
        const unsigned short* cnt = side ? cnt_r : cnt_d;
        unsigned* off = side ? off_r : off_d;
        unsigned s = 0;
        for (int b = seg * 125; b < seg * 125 + 125; b++) s += cnt[b * NWIN + w];
        psum[seg][w] = s;
        __syncthreads();
        if (t < NWIN) {
            unsigned run = 0;
            for (int sg = 0; sg < 8; sg++) { segbase[sg][t] = run; run += psum[sg][t]; }
            wtot[t] = run;
        }
        __syncthreads();
        if (t == 0) {
            unsigned run = 0;
            for (int w2 = 0; w2 < NWIN; w2++) { Wl[w2] = run; run += wtot[w2]; }
            Wl[NWIN] = run;                           // = NIDX
        }
        __syncthreads();
        unsigned run2 = Wl[w] + segbase[seg][w];
        for (int b = seg * 125; b < seg * 125 + 125; b++) {
            off[b * NWIN + w] = run2;
            run2 += cnt[b * NWIN + w];
        }
        if (t < NWIN + 1) Wg[side * (NWIN + 1) + t] = Wl[t];
        __syncthreads();
    }
}

// Node 3: place samples into exact sorted slots (LDS cursors; every slot
// written once; within-run order benign for order-independent counting).
__global__ __launch_bounds__(256) void place_kernel(
    const int* __restrict__ pdArr, const int* __restrict__ prArr,
    const unsigned* __restrict__ off_d, const unsigned* __restrict__ off_r,
    unsigned short* __restrict__ sorted_d, unsigned short* __restrict__ sorted_r)
{
    __shared__ unsigned cur[NWIN];
    const int b = blockIdx.x, t = threadIdx.x;

    for (int k = t; k < NWIN; k += 256) cur[k] = off_d[b * NWIN + k];
    __syncthreads();
    for (int i = t; i < CH_I4; i += 256) {
        const int4 p4 = ((const int4*)pdArr)[b * CH_I4 + i];
        const int pd[4] = {p4.x, p4.y, p4.z, p4.w};
#pragma unroll
        for (int k = 0; k < 4; k++) {
            const unsigned pos = atomicAdd(&cur[pd[k] >> 15], 1u);
            sorted_d[pos] = (unsigned short)(pd[k] & 32767);
        }
    }
    __syncthreads();
    for (int k = t; k < NWIN; k += 256) cur[k] = off_r[b * NWIN + k];
    __syncthreads();
    for (int i = t; i < CH_I4; i += 256) {
        const int4 p4 = ((const int4*)prArr)[b * CH_I4 + i];
        const int pr[4] = {p4.x, p4.y, p4.z, p4.w};
#pragma unroll
        for (int k = 0; k < 4; k++) {
            const unsigned pos = atomicAdd(&cur[pr[k] >> 15], 1u);
            sorted_r[pos] = (unsigned short)(pr[k] & 32767);
        }
    }
}

// Node 4: LDS count-map histogram, QUARTER-WINDOW split (R13). R12 counters:
// 84us at 0.95 TB/s, occupancy 19% — latency-bound at 512 blocks x 35KB LDS.
// Now block = (win, quarter, side): 1024 blocks, 8KB map + 3KB lhist -> ~50%
// occupancy. Each block scans the window's entry list, keeps its quarter
// (4x entry-read dup, L2-friendly ~+24MB), sweeps 8192 pixels sequentially.
// d-side writes flags for its quarter. Bin-0 in registers; 16-copy flush.
__global__ __launch_bounds__(256) void whist2_kernel(
    const float* __restrict__ ref, const float* __restrict__ tgt,
    const float* __restrict__ msrc, const float* __restrict__ mtar,
    const unsigned short* __restrict__ sorted_d, const unsigned short* __restrict__ sorted_r,
    const unsigned* __restrict__ Wg,
    unsigned char* __restrict__ flags, unsigned* __restrict__ hist)
{
    __shared__ unsigned cnt32[2048];        // u8[8192] count map, 8 KB
    __shared__ unsigned lhist[3 * BINS];    // this side's 3 channels

    const int b = blockIdx.x, t = threadIdx.x;
    const int side = b & 1, quarter = (b >> 1) & 3, win = b >> 3;

    for (int k = t; k < 2048; k += 256) cnt32[k] = 0;
    for (int k = t; k < 3 * BINS; k += 256) lhist[k] = 0;
    __syncthreads();

    const unsigned e0 = Wg[side * (NWIN + 1) + win];
    const unsigned e1 = Wg[side * (NWIN + 1) + win + 1];
    const unsigned short* se = side ? sorted_r : sorted_d;
    for (unsigned e = e0 + t; e < e1; e += 256) {
        const unsigned lo = se[e];
        if ((int)(lo >> 13) == quarter) {
            const unsigned q = lo & 8191u;
            atomicAdd(&cnt32[q >> 2], 1u << ((q & 3) * 8));
        }
    }
    __syncthreads();

    const float* img = side ? tgt : ref;
    const float* msk = side ? mtar : msrc;
    const int P0 = (win << 15) + quarter * 8192;  // quarter-window base pixel
    unsigned z0 = 0, z1 = 0, z2 = 0;

    for (int j = t; j < 2048; j += 256) {         // 2048 words x 4 pixels
        const unsigned cw = cnt32[j];
        const int p = P0 + j * 4;
        if (side == 0) {
            const uchar4 f = make_uchar4((cw & 255u) ? 1 : 0, ((cw >> 8) & 255u) ? 1 : 0,
                                         ((cw >> 16) & 255u) ? 1 : 0, (cw >> 24) ? 1 : 0);
            *(uchar4*)(flags + p) = f;
        }
        if (cw == 0) continue;
        const float4 m4 = *(const float4*)(msk + p);
        const float4 v0 = *(const float4*)(img + p);
        const float4 v1 = *(const float4*)(img + HH + p);
        const float4 v2 = *(const float4*)(img + 2 * HH + p);
        const float m[4]  = {m4.x, m4.y, m4.z, m4.w};
        const float a0[4] = {v0.x, v0.y, v0.z, v0.w};
        const float a1[4] = {v1.x, v1.y, v1.z, v1.w};
        const float a2[4] = {v2.x, v2.y, v2.z, v2.w};
#pragma unroll
        for (int k = 0; k < 4; k++) {
            const unsigned c = (cw >> (k * 8)) & 255u;
            if (!c) continue;
            const float mm = m[k];
            // validated reference op order: ((x+1)*0.5)*255, then * mask
            const float f0 = ((a0[k] + 1.0f) * 0.5f) * 255.0f * mm;
            const float f1 = ((a1[k] + 1.0f) * 0.5f) * 255.0f * mm;
            const float f2 = ((a2[k] + 1.0f) * 0.5f) * 255.0f * mm;
            const unsigned b0 = (unsigned)(int)fminf(fmaxf(floorf(f0), 0.0f), 255.0f);
            const unsigned b1 = (unsigned)(int)fminf(fmaxf(floorf(f1), 0.0f), 255.0f);
            const unsigned b2 = (unsigned)(int)fminf(fmaxf(floorf(f2), 0.0f), 255.0f);
            if (b0) atomicAdd(&lhist[           b0], c); else z0 += c;
            if (b1) atomicAdd(&lhist[1 * BINS + b1], c); else z1 += c;
            if (b2) atomicAdd(&lhist[2 * BINS + b2], c); else z2 += c;
        }
    }
    if (z0) atomicAdd(&lhist[0 * BINS], z0);
    if (z1) atomicAdd(&lhist[1 * BINS], z1);
    if (z2) atomicAdd(&lhist[2 * BINS], z2);
    __syncthreads();
    unsigned* h = hist + (b & (NCOPY - 1)) * (6 * BINS) + side * (3 * BINS);
    for (int k = t; k < 3 * BINS; k += 256) {
        const unsigned v = lhist[k];
        if (v) atomicAdd(&h[k], v);
    }
}

// Node 5: transfer table (1 block). Validated logic unchanged.
__global__ __launch_bounds__(256) void table_kernel(
    const unsigned* __restrict__ hist, float* __restrict__ tabg)
{
    __shared__ float    cdf[6 * BINS];
    __shared__ unsigned wsum[4];

    const int t    = threadIdx.x;
    const int lane = t & 63;
    const int wid  = t >> 6;

    for (int ch = 0; ch < 6; ch++) {
        unsigned x = 0;
#pragma unroll
        for (int cp = 0; cp < NCOPY; cp++) x += hist[cp * (6 * BINS) + ch * BINS + t];
#pragma unroll
        for (int d = 1; d < 64; d <<= 1) {
            const unsigned y = __shfl_up(x, d, 64);
            if (lane >= d) x += y;
        }
        if (lane == 63) wsum[wid] = x;
        __syncthreads();
        unsigned prefix = 0;
        for (int w = 0; w < wid; w++) prefix += wsum[w];
        x += prefix;
        cdf[ch * BINS + t] = (float)x / 2000000.0f;   // exact int < 2^24, single rounding
        __syncthreads();
    }
    for (int c = 0; c < 3; c++) {
        float o;
        if (t == 0)             o = 0.0f;
        else if (t == BINS - 1) o = 255.0f;
        else {
            const float v = cdf[c * BINS + t];
            const float* arr = cdf + (3 + c) * BINS;
            int lo = 0, hi = 256;   // lower_bound
            while (lo < hi) { const int mid = (lo + hi) >> 1; if (arr[mid] < v) lo = mid + 1; else hi = mid; }
            const int J0 = ((lo > 1) ? lo : 1) - 1;
            int lo2 = 0, hi2 = 256; // upper_bound
            while (lo2 < hi2) { const int mid = (lo2 + hi2) >> 1; if (arr[mid] <= v) lo2 = mid + 1; else hi2 = mid; }
            const int J1 = ((lo2 - 1) < 254 ? (lo2 - 1) : 254);
            const bool found = (lo2 >= 1) && (J0 <= J1);
            o = found ? (float)(J0 + 1) : (float)t;
        }
        tabg[c * BINS + t] = o;
    }
}

// Node 6: streaming loss (validated logic; flags byte array).
__global__ __launch_bounds__(256) void tabloss_kernel(
    const float* __restrict__ inp, const float* __restrict__ ref,
    const float* __restrict__ msrc, const float* __restrict__ tabg,
    const unsigned char* __restrict__ flags, double* __restrict__ partials)
{
    __shared__ float  tab[3 * BINS];
    __shared__ double red[256];

    const int t = threadIdx.x;
    for (int k = t; k < 3 * BINS; k += 256) tab[k] = tabg[k];
    __syncthreads();

    double local = 0.0;
    const int stride = gridDim.x * 256;
    for (int g = blockIdx.x * 256 + t; g < HH / 4; g += stride) {
        const int p = g * 4;
        const float4 mv = *(const float4*)(msrc + p);
        const uchar4 fw = *(const uchar4*)(flags + p);
        const unsigned samp[4] = {fw.x, fw.y, fw.z, fw.w};
        const float m[4] = {mv.x, mv.y, mv.z, mv.w};
#pragma unroll
        for (int c = 0; c < 3; c++) {
            const float4 rv = *(const float4*)(ref + c * HH + p);
            const float4 iv = *(const float4*)(inp + c * HH + p);
            const float r[4] = {rv.x, rv.y, rv.z, rv.w};
            const float x4[4] = {iv.x, iv.y, iv.z, iv.w};
            float s = 0.0f;
#pragma unroll
            for (int k = 0; k < 4; k++) {
                const float mm = m[k];
                const float refm = ((r[k] + 1.0f) * 0.5f) * 255.0f * mm;
                const float inpm = ((x4[k] + 1.0f) * 0.5f) * 255.0f * mm;
                float matchv;
                if (samp[k]) {
                    const int bidx = (int)fminf(fmaxf(refm, 0.0f), 255.0f);
                    matchv = tab[c * BINS + bidx];
                } else {
                    matchv = refm;
                }
                const float dd = inpm - matchv * mm;
                s += dd * dd;
            }
            local += (double)s;
        }
    }
    red[t] = local;
    __syncthreads();
    for (int s2 = 128; s2 > 0; s2 >>= 1) {
        if (t < s2) red[t] += red[t + s2];
        __syncthreads();
    }
    if (t == 0) partials[blockIdx.x] = red[0];
}

// Node 7: single-block finalize.
__global__ __launch_bounds__(256) void finalize_kernel(
    const double* __restrict__ partials, float* __restrict__ out)
{
    const int t = threadIdx.x;
    double s = 0.0;
    for (int k = t; k < TL_BLOCKS; k += 256) s += partials[k];
    __shared__ double red[256];
    red[t] = s;
    __syncthreads();
    for (int s2 = 128; s2 > 0; s2 >>= 1) {
        if (t < s2) red[t] += red[t + s2];
        __syncthreads();
    }
    if (t == 0) out[0] = (float)(red[0] / (double)(3 * HH));
}

extern "C" void kernel_launch(void* const* d_in, const int* in_sizes, int n_in,
                              void* d_out, int out_size, void* d_ws, size_t ws_size,
                              hipStream_t stream)
{
    const float* input_data  = (const float*)d_in[0];
    const float* target_data = (const float*)d_in[1];
    const float* mask_src    = (const float*)d_in[2];
    const float* mask_tar    = (const float*)d_in[3];
    const int*   i0          = (const int*)d_in[4];
    const int*   i1          = (const int*)d_in[5];
    const int*   i2          = (const int*)d_in[6];
    const int*   i3          = (const int*)d_in[7];
    const float* ref_data    = (const float*)d_in[8];
    float* out = (float*)d_out;

    char* ws = (char*)d_ws;
    double*         partials = (double*)(ws + PART_OFF);
    float*          tabg     = (float*)(ws + TAB_OFF);
    unsigned*       Wg       = (unsigned*)(ws + WGL_OFF);
    unsigned*       hist     = (unsigned*)(ws + HIST_OFF);
    unsigned short* cnt_d    = (unsigned short*)(ws + CNT_D_OFF);
    unsigned short* cnt_r    = (unsigned short*)(ws + CNT_R_OFF);
    unsigned*       off_d    = (unsigned*)(ws + OFF_D_OFF);
    unsigned*       off_r    = (unsigned*)(ws + OFF_R_OFF);
    unsigned char*  flags    = (unsigned char*)(ws + FLAGS_OFF);
    unsigned short* sorted_d = (unsigned short*)(ws + SORT_D_OFF);
    unsigned short* sorted_r = (unsigned short*)(ws + SORT_R_OFF);
    int*            pdArr    = (int*)(ws + PD_OFF);
    int*            prArr    = (int*)(ws + PR_OFF);

    hipMemsetAsync(ws + HIST_OFF, 0, NCOPY * 6 * BINS * 4, stream);
    flat_kernel<<<NCHUNK, 256, 0, stream>>>(i0, i1, i2, i3, pdArr, prArr, cnt_d, cnt_r);
    off_kernel<<<1, 1024, 0, stream>>>(cnt_d, cnt_r, off_d, off_r, Wg);
    place_kernel<<<NCHUNK, 256, 0, stream>>>(pdArr, prArr, off_d, off_r, sorted_d, sorted_r);
    whist2_kernel<<<8 * NWIN, 256, 0, stream>>>(ref_data, target_data, mask_src, mask_tar,
                                                sorted_d, sorted_r, Wg, flags, hist);
    table_kernel<<<1, 256, 0, stream>>>(hist, tabg);
    tabloss_kernel<<<TL_BLOCKS, 256, 0, stream>>>(input_data, ref_data, mask_src, tabg,
                                                  flags, partials);
    finalize_kernel<<<1, 256, 0, stream>>>(partials, out);
}